// Round 13
// baseline (1294.146 us; speedup 1.0000x reference)
//
#include <hip/hip_runtime.h>
#include <cmath>

#define HIDC   128
#define LAYERS 4
#define IN_C   64
#define OUT_C  64

typedef _Float16 h16x8 __attribute__((ext_vector_type(8)));
typedef _Float16 h16x2 __attribute__((ext_vector_type(2)));
typedef float    f32x4 __attribute__((ext_vector_type(4)));

__device__ __forceinline__ float gelu_f(float x) {
    return 0.5f * x * (1.0f + erff(x * 0.70710678118654752f));
}

__device__ __forceinline__ void cvt8(const float4& a, const float4& b, h16x8& h) {
    h[0]=(_Float16)a.x; h[1]=(_Float16)a.y; h[2]=(_Float16)a.z; h[3]=(_Float16)a.w;
    h[4]=(_Float16)b.x; h[5]=(_Float16)b.y; h[6]=(_Float16)b.z; h[7]=(_Float16)b.w;
}

// ---------------------- fp32 -> fp16 conversion (8/thread) -----------------
__global__ __launch_bounds__(256)
void cvtf16_k(const float* __restrict__ s, _Float16* __restrict__ d, int n) {
    int i = (blockIdx.x * blockDim.x + threadIdx.x) * 8;
    if (i + 8 <= n) {
        float4 a = *(const float4*)(s + i), b = *(const float4*)(s + i + 4);
        h16x8 h; cvt8(a, b, h);
        *(h16x8*)(d + i) = h;
    } else {
        for (int j = i; j < n; ++j) d[j] = (_Float16)s[j];
    }
}

// ------------------------------ CSR build ------------------------------
__global__ void count_deg_k(const int* __restrict__ dst, int* __restrict__ cnt, int E) {
    int i = blockIdx.x * blockDim.x + threadIdx.x;
    if (i < E) atomicAdd(&cnt[dst[i]], 1);
}

__global__ __launch_bounds__(256)
void scan1_k(const int* __restrict__ cnt, int* __restrict__ pref,
             int* __restrict__ bsum, int n) {
    __shared__ int part[256];
    const int b = blockIdx.x, t = threadIdx.x;
    const int i0 = b * 1024 + t * 4;
    int v0 = (i0 + 0 < n) ? cnt[i0 + 0] : 0;
    int v1 = (i0 + 1 < n) ? cnt[i0 + 1] : 0;
    int v2 = (i0 + 2 < n) ? cnt[i0 + 2] : 0;
    int v3 = (i0 + 3 < n) ? cnt[i0 + 3] : 0;
    int s = v0 + v1 + v2 + v3;
    part[t] = s;
    __syncthreads();
    for (int off = 1; off < 256; off <<= 1) {
        int x = (t >= off) ? part[t - off] : 0;
        __syncthreads();
        part[t] += x;
        __syncthreads();
    }
    int excl = part[t] - s;
    if (i0 + 0 < n) pref[i0 + 0] = excl;           excl += v0;
    if (i0 + 1 < n) pref[i0 + 1] = excl;           excl += v1;
    if (i0 + 2 < n) pref[i0 + 2] = excl;           excl += v2;
    if (i0 + 3 < n) pref[i0 + 3] = excl;
    if (t == 255) bsum[b] = part[255];
}

__global__ void scan2_k(const int* __restrict__ bsum, int* __restrict__ boff,
                        int nb, int* __restrict__ rowptr_n) {
    int lane = threadIdx.x;  // one wave
    int carry = 0;
    for (int base = 0; base < nb; base += 64) {
        int i = base + lane;
        int v = (i < nb) ? bsum[i] : 0;
        int incl = v;
        for (int off = 1; off < 64; off <<= 1) {
            int x = __shfl_up(incl, off);
            if (lane >= off) incl += x;
        }
        if (i < nb) boff[i] = carry + incl - v;
        carry += __shfl(incl, 63);
    }
    if (lane == 0) *rowptr_n = carry;   // = E
}

__global__ __launch_bounds__(256)
void scan3_k(int* __restrict__ pref, const int* __restrict__ boff, int n) {
    int i = blockIdx.x * blockDim.x + threadIdx.x;
    if (i < n) pref[i] += boff[i >> 10];
}

__global__ void scatter_k(const int* __restrict__ src, const int* __restrict__ dst,
                          const int* __restrict__ rowptr, int* __restrict__ cnt,
                          int* __restrict__ csrc, int E) {
    int i = blockIdx.x * blockDim.x + threadIdx.x;
    if (i < E) {
        int d = dst[i];
        int pos = rowptr[d] + atomicAdd(&cnt[d], 1);
        csrc[pos] = src[i];
    }
}

// ---------------- direct-from-global MFMA GEMM (no LDS, no barriers) -------
// One wave computes 16 rows x CTN*16 cols of C = A @ W^T + bias.
// A fp16 [M,KT]; W fp16 [NC,KT] (pre-offset to this block's col slab).
// Fragment mapping (verified in LDS version): lane l holds
//   A[row = l&15][k = (l>>4)*8 + j],  B[col = l&15][k = (l>>4)*8 + j].
template<int ACT, bool RES, int CTN, int KT, typename CT>
__device__ __forceinline__ void gdirect(
    const _Float16* __restrict__ A, const _Float16* __restrict__ W,
    const float* __restrict__ bias, const _Float16* __restrict__ resid,
    CT* __restrict__ Cp, int M, int ncs, int wave, int lane, int rowblk)
{
    const int r0  = rowblk * 64 + wave * 16;
    const int l15 = lane & 15;
    const int kof = (lane >> 4) * 8;
    int arow = r0 + l15; if (arow >= M) arow = M - 1;   // clamp (loads safe)
    const _Float16* ap = A + (size_t)arow * KT + kof;
    const _Float16* wp = W + (size_t)l15 * KT + kof;

    f32x4 acc[CTN] = {};
#pragma unroll
    for (int kk = 0; kk < KT / 32; ++kk) {
        h16x8 af = *(const h16x8*)(ap + kk * 32);
#pragma unroll
        for (int ct = 0; ct < CTN; ++ct) {
            h16x8 bf = *(const h16x8*)(wp + (size_t)ct * 16 * KT + kk * 32);
            acc[ct] = __builtin_amdgcn_mfma_f32_16x16x32_f16(af, bf, acc[ct], 0, 0, 0);
        }
    }

    const int rb = r0 + (lane >> 4) * 4;
#pragma unroll
    for (int j = 0; j < 4; ++j) {
        int r = rb + j;
        if (r >= M) continue;
        size_t ro = (size_t)r * ncs;
#pragma unroll
        for (int ct = 0; ct < CTN; ++ct) {
            int c = ct * 16 + l15;
            float v = acc[ct][j] + bias[c];
            if (ACT) v = gelu_f(v);
            if (RES) v += (float)resid[ro + c];
            Cp[ro + c] = (CT)v;
        }
    }
}

template<int ACT, bool RES, int CTN, int KT, typename CT>
__global__ __launch_bounds__(256)
void gemm_dir_k(const _Float16* __restrict__ A, const _Float16* __restrict__ W,
                const float* __restrict__ bias, const _Float16* __restrict__ resid,
                CT* __restrict__ C, int M, int ncs) {
    const int lane = threadIdx.x & 63, wave = threadIdx.x >> 6;
    const size_t cb = (size_t)blockIdx.x * (CTN * 16);
    gdirect<ACT, RES, CTN, KT, CT>(A, W + cb * KT, bias + cb,
                                   resid ? resid + cb : resid, C + cb,
                                   M, ncs, wave, lane, blockIdx.y);
}

// qkvs: blockIdx.x selects projection; outputs qh [N,128], kv [N,256] (k|v), sbh [N,128]
__global__ __launch_bounds__(256)
void qkvs_dir_k(const _Float16* __restrict__ A,
                const _Float16* __restrict__ Wq, const _Float16* __restrict__ Wk,
                const _Float16* __restrict__ Wv, const _Float16* __restrict__ Ws,
                const float* __restrict__ bq, const float* __restrict__ bk,
                const float* __restrict__ bv, const float* __restrict__ bs,
                _Float16* __restrict__ qh, _Float16* __restrict__ kv,
                _Float16* __restrict__ sbh, int M) {
    const int lane = threadIdx.x & 63, wave = threadIdx.x >> 6;
    const int proj = blockIdx.x;
    const _Float16* W = (proj == 0) ? Wq : (proj == 1) ? Wk : (proj == 2) ? Wv : Ws;
    const float*    b = (proj == 0) ? bq : (proj == 1) ? bk : (proj == 2) ? bv : bs;
    _Float16* out; int ncs;
    if      (proj == 0) { out = qh;       ncs = 128; }
    else if (proj == 1) { out = kv;       ncs = 256; }
    else if (proj == 2) { out = kv + 128; ncs = 256; }
    else                { out = sbh;      ncs = 128; }
    gdirect<0, false, 8, 128, _Float16>(A, W, b, nullptr, out, M, ncs, wave, lane, blockIdx.y);
}

// ---- fused attention + beta gate + residual + LN (all-fp16 operands) ------
__global__ __launch_bounds__(256)
void attn_ln_k(const _Float16* __restrict__ qh, const _Float16* __restrict__ kv,
               const int* __restrict__ rowptr, const int* __restrict__ csrc,
               const _Float16* __restrict__ xr, const _Float16* __restrict__ res,
               const float* __restrict__ Wb, const float* __restrict__ g_,
               const float* __restrict__ b_, _Float16* __restrict__ out, int n) {
    int node = (int)((blockIdx.x * (size_t)blockDim.x + threadIdx.x) >> 6);
    int lane = threadIdx.x & 63;
    if (node >= n) return;
    const int g = lane & 7;     // edge slot
    const int h = lane >> 3;    // head

    const _Float16* qp = qh + (size_t)node * 128 + h * 16;
    h16x8 q0 = *(const h16x8*)(qp);
    h16x8 q1 = *(const h16x8*)(qp + 8);

    float ssum = 0.f;
    float acc[16] = {};
    const int e0 = rowptr[node], e1 = rowptr[node + 1];
    for (int eb = e0; eb < e1; eb += 8) {
        int e = eb + g;
        bool val = (e < e1);
        int s = csrc[val ? e : (e1 - 1)];
        const _Float16* kp = kv + (size_t)s * 256 + h * 16;
        h16x8 k0 = *(const h16x8*)(kp);
        h16x8 k1 = *(const h16x8*)(kp + 8);
        h16x8 v0 = *(const h16x8*)(kp + 128);
        h16x8 v1 = *(const h16x8*)(kp + 136);
        float d = 0.f;
#pragma unroll
        for (int j = 0; j < 8; ++j) d += (float)k0[j] * (float)q0[j];
#pragma unroll
        for (int j = 0; j < 8; ++j) d += (float)k1[j] * (float)q1[j];
        float w = val ? __expf(d * 0.25f) : 0.f;
        ssum += w;
#pragma unroll
        for (int j = 0; j < 8; ++j) acc[j]     += w * (float)v0[j];
#pragma unroll
        for (int j = 0; j < 8; ++j) acc[8 + j] += w * (float)v1[j];
    }
#pragma unroll
    for (int m = 1; m < 8; m <<= 1) {
        ssum += __shfl_xor(ssum, m);
#pragma unroll
        for (int j = 0; j < 16; ++j) acc[j] += __shfl_xor(acc[j], m);
    }
    float inv = 1.f / (ssum + 1e-16f);
    const bool s0b = g & 1, s1b = g & 2, s2b = g & 4;
    float t0 = s0b ? acc[2]  : acc[0],  t1 = s0b ? acc[6]  : acc[4];
    float t2 = s0b ? acc[10] : acc[8],  t3 = s0b ? acc[14] : acc[12];
    float u0 = s1b ? t1 : t0,           u1 = s1b ? t3 : t2;
    float ox = (s2b ? u1 : u0) * inv;
    float p0 = s0b ? acc[3]  : acc[1],  p1 = s0b ? acc[7]  : acc[5];
    float p2 = s0b ? acc[11] : acc[9],  p3 = s0b ? acc[15] : acc[13];
    float w0 = s1b ? p1 : p0,           w1 = s1b ? p3 : p2;
    float oy = (s2b ? w1 : w0) * inv;

    size_t base = (size_t)node * HIDC + lane * 2;
    int c = lane * 2;
    h16x2 xv = *(const h16x2*)(xr + base);
    float rx = (float)xv[0], ry = (float)xv[1];
    float2 wb0 = *(const float2*)(Wb + c);
    float2 wb1 = *(const float2*)(Wb + HIDC + c);
    float2 wb2 = *(const float2*)(Wb + 2 * HIDC + c);
    float part = ox * wb0.x + oy * wb0.y
               + rx * wb1.x + ry * wb1.y
               + (ox - rx) * wb2.x + (oy - ry) * wb2.y;
#pragma unroll
    for (int mk = 1; mk < 64; mk <<= 1) part += __shfl_xor(part, mk);
    float beta = 1.f / (1.f + __expf(-part));
    h16x2 rv = *(const h16x2*)(res + base);
    float tx = beta * rx + (1.f - beta) * ox + (float)rv[0];
    float ty = beta * ry + (1.f - beta) * oy + (float)rv[1];
    float sum = tx + ty;
#pragma unroll
    for (int mk = 1; mk < 64; mk <<= 1) sum += __shfl_xor(sum, mk);
    float mean = sum * (1.f / 128.f);
    float dx = tx - mean, dy = ty - mean;
    float vs = dx * dx + dy * dy;
#pragma unroll
    for (int mk = 1; mk < 64; mk <<= 1) vs += __shfl_xor(vs, mk);
    float rstd = 1.f / sqrtf(vs * (1.f / 128.f) + 1e-5f);
    float2 gg = *(const float2*)(g_ + c);
    float2 bb = *(const float2*)(b_ + c);
    h16x2 oo;
    oo[0] = (_Float16)(dx * rstd * gg.x + bb.x);
    oo[1] = (_Float16)(dy * rstd * gg.y + bb.y);
    *(h16x2*)(out + base) = oo;
}

// ------------------------------ host launch ------------------------------
extern "C" void kernel_launch(void* const* d_in, const int* in_sizes, int n_in,
                              void* d_out, int out_size, void* d_ws, size_t ws_size,
                              hipStream_t stream) {
    const float* x    = (const float*)d_in[0];
    const int*   ei   = (const int*)d_in[1];
    const float* Wi   = (const float*)d_in[2];
    const float* bi   = (const float*)d_in[3];
    const float* Wq   = (const float*)d_in[4];
    const float* bq   = (const float*)d_in[5];
    const float* Wk   = (const float*)d_in[6];
    const float* bk   = (const float*)d_in[7];
    const float* Wv   = (const float*)d_in[8];
    const float* bv   = (const float*)d_in[9];
    const float* Ws_  = (const float*)d_in[10];
    const float* bs   = (const float*)d_in[11];
    const float* Wbeta= (const float*)d_in[12];
    const float* ln_g = (const float*)d_in[13];
    const float* ln_b = (const float*)d_in[14];
    const float* W1   = (const float*)d_in[15];
    const float* b1   = (const float*)d_in[16];
    const float* W2   = (const float*)d_in[17];
    const float* b2   = (const float*)d_in[18];
    const float* Wo   = (const float*)d_in[19];
    const float* bo   = (const float*)d_in[20];
    float* outp = (float*)d_out;

    const int Nn = in_sizes[0] / IN_C;   // 50000
    const int Ee = in_sizes[1] / 2;      // 600000
    const int* srcI = ei;
    const int* dstI = ei + Ee;

    // ---- workspace layout (fp16-dominant) ----
    _Float16* f16 = (_Float16*)d_ws;
    size_t Nf = (size_t)Nn;
    _Float16* h    = f16;                 // N*128
    _Float16* h2   = h    + Nf * 128;     // N*128
    _Float16* qh   = h2   + Nf * 128;     // N*128
    _Float16* kv   = qh   + Nf * 128;     // N*256
    _Float16* sbh  = kv   + Nf * 256;     // N*128
    _Float16* ffn  = qh;                  // [N,512] aliases qh|kv|sbh exactly
    _Float16* xh   = sbh  + Nf * 128;     // N*64
    _Float16* Wih  = xh   + Nf * 64;      // 128*64
    _Float16* Wqh  = Wih  + 128 * 64;     // 4*128*128
    _Float16* Wkh  = Wqh  + LAYERS * 128 * 128;
    _Float16* Wvh  = Wkh  + LAYERS * 128 * 128;
    _Float16* Wsh  = Wvh  + LAYERS * 128 * 128;
    _Float16* W1h  = Wsh  + LAYERS * 128 * 128;   // 4*512*128
    _Float16* W2h  = W1h  + LAYERS * 512 * 128;   // 4*128*512
    _Float16* Woh  = W2h  + LAYERS * 128 * 512;   // 64*128
    int* rowptr = (int*)(Woh + 64 * 128);
    int* cnt    = rowptr + (Nn + 1);
    int* csrc   = cnt + Nn;
    int* bsum   = csrc + Ee;
    int* boff   = bsum + 1024;

    dim3 blk(256);
    auto cvtgrid = [](int n) { return dim3((n / 8 + 255) / 256); };

    // ---- one-time (per launch) fp32 -> fp16 conversions ----
    cvtf16_k<<<cvtgrid(Nn * IN_C), blk, 0, stream>>>(x, xh, Nn * IN_C);
    cvtf16_k<<<cvtgrid(128 * 64), blk, 0, stream>>>(Wi, Wih, 128 * 64);
    cvtf16_k<<<cvtgrid(LAYERS * 128 * 128), blk, 0, stream>>>(Wq, Wqh, LAYERS * 128 * 128);
    cvtf16_k<<<cvtgrid(LAYERS * 128 * 128), blk, 0, stream>>>(Wk, Wkh, LAYERS * 128 * 128);
    cvtf16_k<<<cvtgrid(LAYERS * 128 * 128), blk, 0, stream>>>(Wv, Wvh, LAYERS * 128 * 128);
    cvtf16_k<<<cvtgrid(LAYERS * 128 * 128), blk, 0, stream>>>(Ws_, Wsh, LAYERS * 128 * 128);
    cvtf16_k<<<cvtgrid(LAYERS * 512 * 128), blk, 0, stream>>>(W1, W1h, LAYERS * 512 * 128);
    cvtf16_k<<<cvtgrid(LAYERS * 128 * 512), blk, 0, stream>>>(W2, W2h, LAYERS * 128 * 512);
    cvtf16_k<<<cvtgrid(64 * 128), blk, 0, stream>>>(Wo, Woh, 64 * 128);

    // ---- CSR build ----
    const int nb = (Nn + 1023) / 1024;
    hipMemsetAsync(cnt, 0, Nn * sizeof(int), stream);
    count_deg_k<<<(Ee + 255) / 256, 256, 0, stream>>>(dstI, cnt, Ee);
    scan1_k<<<nb, 256, 0, stream>>>(cnt, rowptr, bsum, Nn);
    scan2_k<<<1, 64, 0, stream>>>(bsum, boff, nb, rowptr + Nn);
    scan3_k<<<(Nn + 255) / 256, 256, 0, stream>>>(rowptr, boff, Nn);
    hipMemsetAsync(cnt, 0, Nn * sizeof(int), stream);
    scatter_k<<<(Ee + 255) / 256, 256, 0, stream>>>(srcI, dstI, rowptr, cnt, csrc, Ee);

    const int rblk = (Nn + 63) / 64;     // 782 row-blocks (64 rows each)
    int nwaveblk = (Nn + 3) / 4;

    // input projection: h = gelu(xh @ Wih^T + bi), K=64
    gemm_dir_k<1, false, 8, 64, _Float16><<<dim3(1, rblk), blk, 0, stream>>>(xh, Wih, bi, nullptr, h, Nn, HIDC);

    for (int l = 0; l < LAYERS; ++l) {
        const _Float16* Wq_l = Wqh + (size_t)l * 128 * 128;
        const _Float16* Wk_l = Wkh + (size_t)l * 128 * 128;
        const _Float16* Wv_l = Wvh + (size_t)l * 128 * 128;
        const _Float16* Ws_l = Wsh + (size_t)l * 128 * 128;
        const float* bq_l = bq + (size_t)l * HIDC;
        const float* bk_l = bk + (size_t)l * HIDC;
        const float* bv_l = bv + (size_t)l * HIDC;
        const float* bs_l = bs + (size_t)l * HIDC;
        const float* Wb_l = Wbeta + (size_t)l * 3 * HIDC;
        const float* g_l  = ln_g + (size_t)l * HIDC;
        const float* b_l  = ln_b + (size_t)l * HIDC;
        const _Float16* W1_l = W1h + (size_t)l * 512 * 128;
        const _Float16* W2_l = W2h + (size_t)l * 128 * 512;
        const float* b1_l = b1 + (size_t)l * 4 * HIDC;
        const float* b2_l = b2 + (size_t)l * HIDC;

        // Q/K/V/S in one dispatch (grid.x = projection)
        qkvs_dir_k<<<dim3(4, rblk), blk, 0, stream>>>(h, Wq_l, Wk_l, Wv_l, Ws_l,
                                                      bq_l, bk_l, bv_l, bs_l,
                                                      qh, kv, sbh, Nn);

        attn_ln_k<<<nwaveblk, blk, 0, stream>>>(qh, kv, rowptr, csrc,
                                                sbh, h, Wb_l, g_l, b_l, h2, Nn);

        // FFN1: ffn = gelu(h2 @ W1^T + b1), NC=512 via grid.x=4 col slabs
        gemm_dir_k<1, false, 8, 128, _Float16><<<dim3(4, rblk), blk, 0, stream>>>(h2, W1_l, b1_l, nullptr, ffn, Nn, 4 * HIDC);
        // FFN2: h = ffn @ W2^T + b2 + h2, K=512
        gemm_dir_k<0, true, 8, 512, _Float16><<<dim3(1, rblk), blk, 0, stream>>>(ffn, W2_l, b2_l, h2, h, Nn, HIDC);
    }

    // output projection: out(fp32) = h @ Wo^T + bo, NC=64 (CTN=4)
    gemm_dir_k<0, false, 4, 128, float><<<dim3(1, rblk), blk, 0, stream>>>(h, Woh, bo, nullptr, outp, Nn, OUT_C);
}

// Round 14
// 1091.622 us; speedup vs baseline: 1.1855x; 1.1855x over previous
//
#include <hip/hip_runtime.h>
#include <cmath>

#define HIDC   128
#define LAYERS 4
#define IN_C   64
#define OUT_C  64

typedef _Float16 h16x8 __attribute__((ext_vector_type(8)));
typedef _Float16 h16x2 __attribute__((ext_vector_type(2)));
typedef float    f32x4 __attribute__((ext_vector_type(4)));

__device__ __forceinline__ float gelu_f(float x) {
    return 0.5f * x * (1.0f + erff(x * 0.70710678118654752f));
}

__device__ __forceinline__ void cvt8(const float4& a, const float4& b, h16x8& h) {
    h[0]=(_Float16)a.x; h[1]=(_Float16)a.y; h[2]=(_Float16)a.z; h[3]=(_Float16)a.w;
    h[4]=(_Float16)b.x; h[5]=(_Float16)b.y; h[6]=(_Float16)b.z; h[7]=(_Float16)b.w;
}
__device__ __forceinline__ void load16(const float* p, _Float16* d) {
    float4 v0 = *(const float4*)p,     v1 = *(const float4*)(p + 4);
    float4 v2 = *(const float4*)(p+8), v3 = *(const float4*)(p + 12);
    h16x8 h0, h1; cvt8(v0, v1, h0); cvt8(v2, v3, h1);
    *(h16x8*)d = h0; *(h16x8*)(d + 8) = h1;
}
__device__ __forceinline__ void load16(const _Float16* p, _Float16* d) {
    *(h16x8*)d = *(const h16x8*)p; *(h16x8*)(d + 8) = *(const h16x8*)(p + 8);
}
__device__ __forceinline__ void zero16(_Float16* d) {
    h16x8 z = {};
    *(h16x8*)d = z; *(h16x8*)(d + 8) = z;
}

// -------- one-dispatch W1/W2 fp32->fp16 (grid.y: 0=W1, 1=W2) --------------
__global__ __launch_bounds__(256)
void cvtw_k(const float* __restrict__ W1, _Float16* __restrict__ W1h,
            const float* __restrict__ W2, _Float16* __restrict__ W2h, int n) {
    const float* s = blockIdx.y ? W2 : W1;
    _Float16*    d = blockIdx.y ? W2h : W1h;
    int i = (blockIdx.x * blockDim.x + threadIdx.x) * 8;
    if (i + 8 <= n) {
        float4 a = *(const float4*)(s + i), b = *(const float4*)(s + i + 4);
        h16x8 h; cvt8(a, b, h);
        *(h16x8*)(d + i) = h;
    }
}

// ------------------------------ CSR build ------------------------------
__global__ void count_deg_k(const int* __restrict__ dst, int* __restrict__ cnt, int E) {
    int i = blockIdx.x * blockDim.x + threadIdx.x;
    if (i < E) atomicAdd(&cnt[dst[i]], 1);
}

// scan1 also zeroes cnt (read-then-clear) so scatter can reuse it
__global__ __launch_bounds__(256)
void scan1_k(int* __restrict__ cnt, int* __restrict__ pref,
             int* __restrict__ bsum, int n) {
    __shared__ int part[256];
    const int b = blockIdx.x, t = threadIdx.x;
    const int i0 = b * 1024 + t * 4;
    int v0 = (i0 + 0 < n) ? cnt[i0 + 0] : 0;
    int v1 = (i0 + 1 < n) ? cnt[i0 + 1] : 0;
    int v2 = (i0 + 2 < n) ? cnt[i0 + 2] : 0;
    int v3 = (i0 + 3 < n) ? cnt[i0 + 3] : 0;
    if (i0 + 0 < n) cnt[i0 + 0] = 0;
    if (i0 + 1 < n) cnt[i0 + 1] = 0;
    if (i0 + 2 < n) cnt[i0 + 2] = 0;
    if (i0 + 3 < n) cnt[i0 + 3] = 0;
    int s = v0 + v1 + v2 + v3;
    part[t] = s;
    __syncthreads();
    for (int off = 1; off < 256; off <<= 1) {
        int x = (t >= off) ? part[t - off] : 0;
        __syncthreads();
        part[t] += x;
        __syncthreads();
    }
    int excl = part[t] - s;
    if (i0 + 0 < n) pref[i0 + 0] = excl;           excl += v0;
    if (i0 + 1 < n) pref[i0 + 1] = excl;           excl += v1;
    if (i0 + 2 < n) pref[i0 + 2] = excl;           excl += v2;
    if (i0 + 3 < n) pref[i0 + 3] = excl;
    if (t == 255) bsum[b] = part[255];
}

__global__ void scan2_k(const int* __restrict__ bsum, int* __restrict__ boff,
                        int nb, int* __restrict__ rowptr_n) {
    int lane = threadIdx.x;  // one wave
    int carry = 0;
    for (int base = 0; base < nb; base += 64) {
        int i = base + lane;
        int v = (i < nb) ? bsum[i] : 0;
        int incl = v;
        for (int off = 1; off < 64; off <<= 1) {
            int x = __shfl_up(incl, off);
            if (lane >= off) incl += x;
        }
        if (i < nb) boff[i] = carry + incl - v;
        carry += __shfl(incl, 63);
    }
    if (lane == 0) *rowptr_n = carry;   // = E
}

__global__ __launch_bounds__(256)
void scan3_k(int* __restrict__ pref, const int* __restrict__ boff, int n) {
    int i = blockIdx.x * blockDim.x + threadIdx.x;
    if (i < n) pref[i] += boff[i >> 10];
}

__global__ void scatter_k(const int* __restrict__ src, const int* __restrict__ dst,
                          const int* __restrict__ rowptr, int* __restrict__ cnt,
                          int* __restrict__ csrc, int E) {
    int i = blockIdx.x * blockDim.x + threadIdx.x;
    if (i < E) {
        int d = dst[i];
        int pos = rowptr[d] + atomicAdd(&cnt[d], 1);
        csrc[pos] = src[i];
    }
}

// --------------- generic MFMA fp16 GEMM (R8 small-LDS structure) -----------
template<int ACT, bool RES, bool NGUARD, typename AT, typename CT>
__global__ __launch_bounds__(256)
void gemm_f16_k(const AT* __restrict__ A, const float* __restrict__ Wt,
                const float* __restrict__ bias, const float* __restrict__ resid,
                CT* __restrict__ Ct, int M, int ncs, int K) {
    __shared__ __align__(16) _Float16 As[128 * 40];
    __shared__ __align__(16) _Float16 Bs[128 * 40];
    const int tid  = threadIdx.x;
    const int lane = tid & 63;
    const int wave = tid >> 6;
    const int wr = wave >> 1, wc = wave & 1;
    const int row0 = blockIdx.y * 128;
    const int colbase = blockIdx.x * 128;

    f32x4 acc[4][4] = {};

    const int srow = tid >> 1;
    const int skc  = (tid & 1) * 16;
    const int fr   = lane & 15;
    const int fk   = (lane >> 4) * 8;

    for (int k0 = 0; k0 < K; k0 += 32) {
        {
            int gr = row0 + srow;
            _Float16* d = As + srow * 40 + skc;
            if (gr < M) load16(A + (size_t)gr * K + k0 + skc, d);
            else        zero16(d);
        }
        {
            int gc = colbase + srow;
            _Float16* d = Bs + srow * 40 + skc;
            if (!NGUARD || gc < ncs) load16(Wt + (size_t)gc * K + k0 + skc, d);
            else                     zero16(d);
        }
        __syncthreads();
        h16x8 af[4], bf[4];
#pragma unroll
        for (int mi = 0; mi < 4; ++mi)
            af[mi] = *(const h16x8*)(As + (wr * 64 + mi * 16 + fr) * 40 + fk);
#pragma unroll
        for (int ni = 0; ni < 4; ++ni)
            bf[ni] = *(const h16x8*)(Bs + (wc * 64 + ni * 16 + fr) * 40 + fk);
#pragma unroll
        for (int mi = 0; mi < 4; ++mi)
#pragma unroll
            for (int ni = 0; ni < 4; ++ni)
                acc[mi][ni] = __builtin_amdgcn_mfma_f32_16x16x32_f16(af[mi], bf[ni], acc[mi][ni], 0, 0, 0);
        __syncthreads();
    }

    const int rbase = row0 + wr * 64 + ((lane >> 4) * 4);
    const int cbase = colbase + wc * 64 + fr;
#pragma unroll
    for (int mi = 0; mi < 4; ++mi) {
#pragma unroll
        for (int j = 0; j < 4; ++j) {
            int r = rbase + mi * 16 + j;
            if (r >= M) continue;
            size_t rb = (size_t)r * ncs;
#pragma unroll
            for (int ni = 0; ni < 4; ++ni) {
                int c = cbase + ni * 16;
                if (NGUARD && c >= ncs) continue;
                float v = acc[mi][ni][j] + bias[c];
                if (ACT == 1) v = gelu_f(v);
                if (RES) v += resid[rb + c];
                Ct[rb + c] = (CT)v;
            }
        }
    }
}

// --------- fused Q/K/V/S (R8 fat version): stage A once, loop 4 weights -----
__global__ __launch_bounds__(256)
void qkvs_k(const float* __restrict__ A,
            const float* __restrict__ Wq, const float* __restrict__ Wk,
            const float* __restrict__ Wv, const float* __restrict__ Wvs,
            const float* __restrict__ bq, const float* __restrict__ bk,
            const float* __restrict__ bv, const float* __restrict__ bs,
            _Float16* __restrict__ qh, _Float16* __restrict__ kv,
            float* __restrict__ sb, int M) {
    __shared__ __align__(16) _Float16 As[128 * 136];
    __shared__ __align__(16) _Float16 Bs[128 * 136];
    const int tid  = threadIdx.x;
    const int lane = tid & 63;
    const int wave = tid >> 6;
    const int wr = wave >> 1, wc = wave & 1;
    const int row0 = blockIdx.x * 128;
    const int srow  = tid >> 1;
    const int shalf = (tid & 1) * 64;
    const int fr = lane & 15;

    {
        int gr = row0 + srow;
        _Float16* d = As + srow * 136 + shalf;
        if (gr < M) {
            const float* p = A + (size_t)gr * 128 + shalf;
#pragma unroll
            for (int u = 0; u < 4; ++u) load16(p + u * 16, d + u * 16);
        } else {
#pragma unroll
            for (int u = 0; u < 4; ++u) zero16(d + u * 16);
        }
    }

    for (int w = 0; w < 4; ++w) {
        const float* Wp = (w == 0) ? Wq : (w == 1) ? Wk : (w == 2) ? Wv : Wvs;
        const float* bp = (w == 0) ? bq : (w == 1) ? bk : (w == 2) ? bv : bs;
        {
            const float* p = Wp + (size_t)srow * 128 + shalf;
            _Float16* d = Bs + srow * 136 + shalf;
#pragma unroll
            for (int u = 0; u < 4; ++u) load16(p + u * 16, d + u * 16);
        }
        __syncthreads();
        f32x4 acc[4][4] = {};
#pragma unroll
        for (int ks = 0; ks < 4; ++ks) {
            const int fk = ks * 32 + (lane >> 4) * 8;
            h16x8 af[4], bf[4];
#pragma unroll
            for (int mi = 0; mi < 4; ++mi)
                af[mi] = *(const h16x8*)(As + (wr * 64 + mi * 16 + fr) * 136 + fk);
#pragma unroll
            for (int ni = 0; ni < 4; ++ni)
                bf[ni] = *(const h16x8*)(Bs + (wc * 64 + ni * 16 + fr) * 136 + fk);
#pragma unroll
            for (int mi = 0; mi < 4; ++mi)
#pragma unroll
                for (int ni = 0; ni < 4; ++ni)
                    acc[mi][ni] = __builtin_amdgcn_mfma_f32_16x16x32_f16(af[mi], bf[ni], acc[mi][ni], 0, 0, 0);
        }
        __syncthreads();

        const int rbase = row0 + wr * 64 + ((lane >> 4) * 4);
        const int cbase = wc * 64 + fr;
#pragma unroll
        for (int mi = 0; mi < 4; ++mi) {
#pragma unroll
            for (int j = 0; j < 4; ++j) {
                int r = rbase + mi * 16 + j;
                if (r >= M) continue;
#pragma unroll
                for (int ni = 0; ni < 4; ++ni) {
                    int c = cbase + ni * 16;
                    float v = acc[mi][ni][j] + bp[c];
                    if (w == 0)      qh[(size_t)r * 128 + c] = (_Float16)v;
                    else if (w == 1) kv[(size_t)r * 256 + c] = (_Float16)v;
                    else if (w == 2) kv[(size_t)r * 256 + 128 + c] = (_Float16)v;
                    else             sb[(size_t)r * 128 + c] = v;
                }
            }
        }
    }
}

// ---- fused attention + beta gate + residual + LN (R8 version) -------------
__global__ __launch_bounds__(256)
void attn_ln_k(const _Float16* __restrict__ qh, const _Float16* __restrict__ kv,
               const int* __restrict__ rowptr, const int* __restrict__ csrc,
               const float* __restrict__ xr, const float* __restrict__ res,
               const float* __restrict__ Wb, const float* __restrict__ g_,
               const float* __restrict__ b_, float* __restrict__ out, int n) {
    int node = (int)((blockIdx.x * (size_t)blockDim.x + threadIdx.x) >> 6);
    int lane = threadIdx.x & 63;
    if (node >= n) return;
    const int g = lane & 7;     // edge slot
    const int h = lane >> 3;    // head

    const _Float16* qp = qh + (size_t)node * 128 + h * 16;
    h16x8 q0 = *(const h16x8*)(qp);
    h16x8 q1 = *(const h16x8*)(qp + 8);

    float ssum = 0.f;
    float acc[16] = {};
    const int e0 = rowptr[node], e1 = rowptr[node + 1];
    for (int eb = e0; eb < e1; eb += 8) {
        int e = eb + g;
        bool val = (e < e1);
        int s = csrc[val ? e : (e1 - 1)];
        const _Float16* kp = kv + (size_t)s * 256 + h * 16;
        h16x8 k0 = *(const h16x8*)(kp);
        h16x8 k1 = *(const h16x8*)(kp + 8);
        h16x8 v0 = *(const h16x8*)(kp + 128);
        h16x8 v1 = *(const h16x8*)(kp + 136);
        float d = 0.f;
#pragma unroll
        for (int j = 0; j < 8; ++j) d += (float)k0[j] * (float)q0[j];
#pragma unroll
        for (int j = 0; j < 8; ++j) d += (float)k1[j] * (float)q1[j];
        float w = val ? __expf(d * 0.25f) : 0.f;
        ssum += w;
#pragma unroll
        for (int j = 0; j < 8; ++j) acc[j]     += w * (float)v0[j];
#pragma unroll
        for (int j = 0; j < 8; ++j) acc[8 + j] += w * (float)v1[j];
    }
#pragma unroll
    for (int m = 1; m < 8; m <<= 1) {
        ssum += __shfl_xor(ssum, m);
#pragma unroll
        for (int j = 0; j < 16; ++j) acc[j] += __shfl_xor(acc[j], m);
    }
    float inv = 1.f / (ssum + 1e-16f);
    const bool s0b = g & 1, s1b = g & 2, s2b = g & 4;
    float t0 = s0b ? acc[2]  : acc[0],  t1 = s0b ? acc[6]  : acc[4];
    float t2 = s0b ? acc[10] : acc[8],  t3 = s0b ? acc[14] : acc[12];
    float u0 = s1b ? t1 : t0,           u1 = s1b ? t3 : t2;
    float ox = (s2b ? u1 : u0) * inv;
    float p0 = s0b ? acc[3]  : acc[1],  p1 = s0b ? acc[7]  : acc[5];
    float p2 = s0b ? acc[11] : acc[9],  p3 = s0b ? acc[15] : acc[13];
    float w0 = s1b ? p1 : p0,           w1 = s1b ? p3 : p2;
    float oy = (s2b ? w1 : w0) * inv;

    size_t base = (size_t)node * HIDC + lane * 2;
    int c = lane * 2;
    float2 r  = *(const float2*)(xr + base);
    float2 wb0 = *(const float2*)(Wb + c);
    float2 wb1 = *(const float2*)(Wb + HIDC + c);
    float2 wb2 = *(const float2*)(Wb + 2 * HIDC + c);
    float part = ox * wb0.x + oy * wb0.y
               + r.x * wb1.x + r.y * wb1.y
               + (ox - r.x) * wb2.x + (oy - r.y) * wb2.y;
#pragma unroll
    for (int mk = 1; mk < 64; mk <<= 1) part += __shfl_xor(part, mk);
    float beta = 1.f / (1.f + __expf(-part));
    float2 rs = *(const float2*)(res + base);
    float tx = beta * r.x + (1.f - beta) * ox + rs.x;
    float ty = beta * r.y + (1.f - beta) * oy + rs.y;
    float sum = tx + ty;
#pragma unroll
    for (int mk = 1; mk < 64; mk <<= 1) sum += __shfl_xor(sum, mk);
    float mean = sum * (1.f / 128.f);
    float dx = tx - mean, dy = ty - mean;
    float vs = dx * dx + dy * dy;
#pragma unroll
    for (int mk = 1; mk < 64; mk <<= 1) vs += __shfl_xor(vs, mk);
    float rstd = 1.f / sqrtf(vs * (1.f / 128.f) + 1e-5f);
    float2 gg = *(const float2*)(g_ + c);
    float2 bb = *(const float2*)(b_ + c);
    float2 oo = make_float2(dx * rstd * gg.x + bb.x, dy * rstd * gg.y + bb.y);
    *(float2*)(out + base) = oo;
}

// ---- fused FFN: hout = gelu(h2 @ W1^T + b1) @ W2^T + b2 + h2 --------------
// 64-row blocks, 4 waves, each wave owns 16 rows. 32-col ffn chunks;
// GEMM1-chunk C relayout -> GEMM2 A-fragment via 1 KB per-wave LDS scratch
// (same-wave ds ordering; NO barriers). ffn never touches global memory.
__global__ __launch_bounds__(256)
void ffn_fused_k(const float* __restrict__ h2, const _Float16* __restrict__ W1h,
                 const float* __restrict__ b1, const _Float16* __restrict__ W2h,
                 const float* __restrict__ b2, float* __restrict__ hout, int M) {
    __shared__ __align__(16) _Float16 scr[4][16 * 36];
    const int tid = threadIdx.x, lane = tid & 63, wave = tid >> 6;
    const int r0  = blockIdx.x * 64 + wave * 16;
    const int l15 = lane & 15;
    const int g   = lane >> 4;        // 0..3
    const int kof = g * 8;
    _Float16* sw = scr[wave];

    // A-fragments of GEMM1 (h2 rows, fp32 -> fp16), loaded once
    h16x8 a1[4];
    {
        int ar = r0 + l15; if (ar >= M) ar = M - 1;
        const float* ap = h2 + (size_t)ar * 128 + kof;
#pragma unroll
        for (int kk = 0; kk < 4; ++kk) {
            float4 u = *(const float4*)(ap + kk * 32);
            float4 v = *(const float4*)(ap + kk * 32 + 4);
            cvt8(u, v, a1[kk]);
        }
    }

    f32x4 acc2[8] = {};
    for (int c0 = 0; c0 < 512; c0 += 32) {
        // GEMM1 chunk: ffn[:, c0..c0+31]
        f32x4 acc1[2] = {};
#pragma unroll
        for (int ct = 0; ct < 2; ++ct) {
            const _Float16* wp = W1h + (size_t)(c0 + ct * 16 + l15) * 128 + kof;
#pragma unroll
            for (int kk = 0; kk < 4; ++kk) {
                h16x8 bf = *(const h16x8*)(wp + kk * 32);
                acc1[ct] = __builtin_amdgcn_mfma_f32_16x16x32_f16(a1[kk], bf, acc1[ct], 0, 0, 0);
            }
        }
        // bias + gelu -> scratch (C layout: row=g*4+j, col=ct*16+l15)
#pragma unroll
        for (int ct = 0; ct < 2; ++ct) {
            float bv = b1[c0 + ct * 16 + l15];
#pragma unroll
            for (int j = 0; j < 4; ++j)
                sw[(g * 4 + j) * 36 + ct * 16 + l15] = (_Float16)gelu_f(acc1[ct][j] + bv);
        }
        // read back as GEMM2 A-fragment: row=l15, k=kof..kof+7 (same wave,
        // ds ops in order; compiler inserts lgkmcnt for the dependence)
        h16x8 af2 = *(const h16x8*)(sw + l15 * 36 + kof);
        // GEMM2: accumulate into all 128 output cols
#pragma unroll
        for (int ot = 0; ot < 8; ++ot) {
            const _Float16* wp2 = W2h + (size_t)(ot * 16 + l15) * 512 + c0 + kof;
            h16x8 bf = *(const h16x8*)wp2;
            acc2[ot] = __builtin_amdgcn_mfma_f32_16x16x32_f16(af2, bf, acc2[ot], 0, 0, 0);
        }
    }

    // epilogue: row = r0 + g*4 + j, col = ot*16 + l15; + b2 + residual h2
#pragma unroll
    for (int j = 0; j < 4; ++j) {
        int r = r0 + g * 4 + j;
        if (r >= M) continue;
        size_t ro = (size_t)r * 128;
#pragma unroll
        for (int ot = 0; ot < 8; ++ot) {
            int c = ot * 16 + l15;
            hout[ro + c] = acc2[ot][j] + b2[c] + h2[ro + c];
        }
    }
}

// ------------------------------ host launch ------------------------------
extern "C" void kernel_launch(void* const* d_in, const int* in_sizes, int n_in,
                              void* d_out, int out_size, void* d_ws, size_t ws_size,
                              hipStream_t stream) {
    const float* x    = (const float*)d_in[0];
    const int*   ei   = (const int*)d_in[1];
    const float* Wi   = (const float*)d_in[2];
    const float* bi   = (const float*)d_in[3];
    const float* Wq   = (const float*)d_in[4];
    const float* bq   = (const float*)d_in[5];
    const float* Wk   = (const float*)d_in[6];
    const float* bk   = (const float*)d_in[7];
    const float* Wv   = (const float*)d_in[8];
    const float* bv   = (const float*)d_in[9];
    const float* Ws_  = (const float*)d_in[10];
    const float* bs   = (const float*)d_in[11];
    const float* Wbeta= (const float*)d_in[12];
    const float* ln_g = (const float*)d_in[13];
    const float* ln_b = (const float*)d_in[14];
    const float* W1   = (const float*)d_in[15];
    const float* b1   = (const float*)d_in[16];
    const float* W2   = (const float*)d_in[17];
    const float* b2   = (const float*)d_in[18];
    const float* Wo   = (const float*)d_in[19];
    const float* bo   = (const float*)d_in[20];
    float* outp = (float*)d_out;

    const int Nn = in_sizes[0] / IN_C;   // 50000
    const int Ee = in_sizes[1] / 2;      // 600000
    const int* srcI = ei;
    const int* dstI = ei + Ee;

    // ws: h f32 | h2 f32 | qh f16 N*128 | kv f16 N*256 | sb f32 | W1h | W2h | ints
    float* ws = (float*)d_ws;
    size_t n128 = (size_t)Nn * HIDC;
    float*     h   = ws;
    float*     h2  = h  + n128;
    _Float16*  qh  = (_Float16*)(h2 + n128);
    _Float16*  kv  = qh + (size_t)Nn * 128;
    float*     sb  = (float*)(kv + (size_t)Nn * 256);
    _Float16*  W1h = (_Float16*)(sb + n128);          // 4*512*128
    _Float16*  W2h = W1h + (size_t)LAYERS * 512 * 128;
    int* rowptr = (int*)(W2h + (size_t)LAYERS * 128 * 512);
    int* cnt    = rowptr + (Nn + 1);
    int* csrc   = cnt + Nn;
    int* bsum   = csrc + Ee;
    int* boff   = bsum + 1024;

    const int nb = (Nn + 1023) / 1024;   // 49
    dim3 blk(256);

    // weights fp32->fp16, one dispatch (independent of CSR)
    const int wn = LAYERS * 512 * 128;   // 262144 each
    cvtw_k<<<dim3(wn / 8 / 256, 2), blk, 0, stream>>>(W1, W1h, W2, W2h, wn);

    // CSR (6 dispatches: memset, count, scan1[+clear], scan2, scan3, scatter)
    hipMemsetAsync(cnt, 0, Nn * sizeof(int), stream);
    count_deg_k<<<(Ee + 255) / 256, 256, 0, stream>>>(dstI, cnt, Ee);
    scan1_k<<<nb, 256, 0, stream>>>(cnt, rowptr, bsum, Nn);
    scan2_k<<<1, 64, 0, stream>>>(bsum, boff, nb, rowptr + Nn);
    scan3_k<<<(Nn + 255) / 256, 256, 0, stream>>>(rowptr, boff, Nn);
    scatter_k<<<(Ee + 255) / 256, 256, 0, stream>>>(srcI, dstI, rowptr, cnt, csrc, Ee);

    const int mblk = (Nn + 127) / 128;   // 391
    const int fblk = (Nn + 63) / 64;     // 782
    int nwaveblk = (Nn + 3) / 4;

    // input projection: h = gelu(x @ Wi^T + bi), K=64
    gemm_f16_k<1, false, false, float, float><<<dim3(1, mblk), blk, 0, stream>>>(x, Wi, bi, nullptr, h, Nn, HIDC, IN_C);

    for (int l = 0; l < LAYERS; ++l) {
        const float* Wq_l = Wq + (size_t)l * HIDC * HIDC;
        const float* Wk_l = Wk + (size_t)l * HIDC * HIDC;
        const float* Wv_l = Wv + (size_t)l * HIDC * HIDC;
        const float* Ws_l = Ws_ + (size_t)l * HIDC * HIDC;
        const float* bq_l = bq + (size_t)l * HIDC;
        const float* bk_l = bk + (size_t)l * HIDC;
        const float* bv_l = bv + (size_t)l * HIDC;
        const float* bs_l = bs + (size_t)l * HIDC;
        const float* Wb_l = Wbeta + (size_t)l * 3 * HIDC;
        const float* g_l  = ln_g + (size_t)l * HIDC;
        const float* b_l  = ln_b + (size_t)l * HIDC;
        const _Float16* W1_l = W1h + (size_t)l * 512 * 128;
        const _Float16* W2_l = W2h + (size_t)l * 128 * 512;
        const float* b1_l = b1 + (size_t)l * 4 * HIDC;
        const float* b2_l = b2 + (size_t)l * HIDC;

        qkvs_k<<<dim3(mblk), blk, 0, stream>>>(h, Wq_l, Wk_l, Wv_l, Ws_l,
                                               bq_l, bk_l, bv_l, bs_l,
                                               qh, kv, sb, Nn);

        attn_ln_k<<<nwaveblk, blk, 0, stream>>>(qh, kv, rowptr, csrc,
                                                sb, h, Wb_l, g_l, b_l, h2, Nn);

        // fused FFN: h = gelu(h2 @ W1^T + b1) @ W2^T + b2 + h2  (one dispatch)
        ffn_fused_k<<<dim3(fblk), blk, 0, stream>>>(h2, W1_l, b1_l, W2_l, b2_l, h, Nn);
    }

    // output projection: out = h @ Wo^T + bo (NC=64, guarded)
    gemm_f16_k<0, false, true, float, float><<<dim3(1, mblk), blk, 0, stream>>>(h, Wo, bo, nullptr, outp, Nn, OUT_C, HIDC);
}